// Round 1
// 597.101 us; speedup vs baseline: 1.2065x; 1.2065x over previous
//
#include <hip/hip_runtime.h>

#define B_ 4
#define N_ 16384
#define HID_ 512
#define H_ 8
#define M_ 32
#define D_ 64

typedef __attribute__((ext_vector_type(8))) short short8;
typedef __attribute__((ext_vector_type(4))) float f32x4;

__device__ __forceinline__ short f2bf(float f) {
    unsigned u = __float_as_uint(f);
    u += 0x7fffu + ((u >> 16) & 1u);
    return (short)(u >> 16);
}
__device__ __forceinline__ float bf2f(short s) {
    return __uint_as_float(((unsigned)(unsigned short)s) << 16);
}
__device__ __forceinline__ unsigned pack2(float a, float b) {
    return (unsigned)(unsigned short)f2bf(a) | ((unsigned)(unsigned short)f2bf(b) << 16);
}
__device__ __forceinline__ void gl_lds16(const short* g, short* l) {
    __builtin_amdgcn_global_load_lds((const __attribute__((address_space(1))) unsigned*)g,
                                     (__attribute__((address_space(3))) unsigned*)l, 16, 0, 0);
}

// ------------------------- misc outputs + wtq f32->bf16 (16384 elems, grid 64)
__global__ void k_misc(const float* __restrict__ alpha, float* __restrict__ a_out,
                       float* __restrict__ z_out, const float* __restrict__ wtq,
                       short* __restrict__ wtq_bf) {
    int i = blockIdx.x * 256 + threadIdx.x;
    wtq_bf[i] = f2bf(wtq[i]);
    if (blockIdx.x == 0) {
        int t = threadIdx.x;
        if (t < H_) a_out[t] = alpha[t];
        z_out[t] = 0.f;  // 256 = H_*M_
    }
}

// --------------------------------------------- x (f32) -> bf16, streaming convert
__global__ void k_cvt(const float* __restrict__ src, short* __restrict__ dst) {
    int i = blockIdx.x * 256 + threadIdx.x;   // 8 elements per thread
    const f32x4* s = (const f32x4*)(src) + (size_t)i * 2;
    f32x4 a = s[0], b = s[1];
    short8 o;
    o[0] = f2bf(a[0]); o[1] = f2bf(a[1]); o[2] = f2bf(a[2]); o[3] = f2bf(a[3]);
    o[4] = f2bf(b[0]); o[5] = f2bf(b[1]); o[6] = f2bf(b[2]); o[7] = f2bf(b[3]);
    ((short8*)dst)[i] = o;
}

// ------------------------------------------- wkv_w (512x1024 f32) -> (1024x512 bf16)
__global__ void k_wt(const float* __restrict__ w, short* __restrict__ wt) {
    int e = blockIdx.x * 256 + threadIdx.x;   // 524288 total
    int nn = e >> 9, kk = e & 511;
    wt[e] = f2bf(w[kk * 1024 + nn]);
}

// ---------------------------------------------------------------- MFMA GEMM (m97 structure)
template <bool OUT_BF16>
__global__ __launch_bounds__(256, 2)
void mfma_gemm(const short* __restrict__ A, const short* __restrict__ Bt,
               const float* __restrict__ bias, void* __restrict__ Cv,
               int K, int Ncols, int b_stride, int rows_per_b) {
    __shared__ short As[128 * 32];
    __shared__ short Bs[128 * 32];
    const int t = threadIdx.x;
    const int col0 = blockIdx.x * 128;
    const int row0 = blockIdx.y * 128;
    const short* Bblk = Bt;
    if (b_stride) Bblk += (size_t)(row0 / rows_per_b) * (size_t)b_stride;

    const int r_a = t >> 2;
    const int c_a = (t & 3) << 3;
    const short* Ap = A + (size_t)(row0 + r_a) * K + c_a;
    const short* Bp = Bblk + (size_t)(col0 + r_a) * K + c_a;
    short* As0 = &As[t << 3];
    short* Bs0 = &Bs[t << 3];
    const size_t rowskip = (size_t)64 * K;

    const int w = t >> 6;
    const int L = t & 63;
    const int wm = (w >> 1) << 6;
    const int wn = (w & 1) << 6;
    const int lm = L & 15;
    const int lq = L >> 4;

    f32x4 acc[4][4];
#pragma unroll
    for (int i = 0; i < 4; ++i)
#pragma unroll
        for (int j = 0; j < 4; ++j) acc[i][j] = (f32x4){0.f, 0.f, 0.f, 0.f};

    for (int k0 = 0; k0 < K; k0 += 32) {
        gl_lds16(Ap + k0, As0);
        gl_lds16(Ap + k0 + rowskip, As0 + 2048);
        gl_lds16(Bp + k0, Bs0);
        gl_lds16(Bp + k0 + rowskip, Bs0 + 2048);
        __syncthreads();
        short8 af[4], bfr[4];
#pragma unroll
        for (int i = 0; i < 4; ++i)
            af[i] = *(const short8*)&As[((wm + (i << 4) + lm) << 5) + (lq << 3)];
#pragma unroll
        for (int j = 0; j < 4; ++j)
            bfr[j] = *(const short8*)&Bs[((wn + (j << 4) + lm) << 5) + (lq << 3)];
#pragma unroll
        for (int i = 0; i < 4; ++i)
#pragma unroll
            for (int j = 0; j < 4; ++j)
                acc[i][j] = __builtin_amdgcn_mfma_f32_16x16x32_bf16(af[i], bfr[j], acc[i][j], 0, 0, 0);
        __syncthreads();
    }
#pragma unroll
    for (int i = 0; i < 4; ++i) {
#pragma unroll
        for (int j = 0; j < 4; ++j) {
            const int gr = row0 + wm + (i << 4) + (lq << 2);
            const int gc = col0 + wn + (j << 4) + lm;
            const float bv = bias[gc];
#pragma unroll
            for (int r = 0; r < 4; ++r) {
                float v = acc[i][j][r] + bv;
                if constexpr (OUT_BF16)
                    ((short*)Cv)[(size_t)(gr + r) * Ncols + gc] = f2bf(v);
                else
                    ((float*)Cv)[(size_t)(gr + r) * Ncols + gc] = v;
            }
        }
    }
}

// ---------------------------------------------------------------- slice kernel (MFMA)
// One block = (b, h, 256-token chunk), 4 waves.
// Phase 1: S(256x32) = xk(256x64,bf16) . wtq_h^T(64x32,bf16) via mfma 16x16x32.
//   A-frags per-lane from global (kv is L2/L3-warm; each 16B read once, lines fully
//   covered by 4 consecutive g-lanes). Softmax over m in-register: D-layout puts a
//   token's 16 m-values across 16 lanes -> shfl_xor(1,2,4,8) reduce.
// sw_out written from regs: per (nt,mt) the 4 reg-lanes are 4 consecutive n ->
//   f32x4 stores fully covering 64B lines (16 lines/instr, no amplification).
// Phase 2: num(32x64) += wT(32x256,bf16) . xvT(64x256,bf16) via mfma, K=256.
//   wT/xvT in LDS with ^((row&7)<<3) short-index XOR swizzle (row stride 512B would
//   be 16-way bank conflict on ds_read_b128 otherwise - §6 G4 recipe).
// NO atomics: per-block partials -> pnum/pws (overlaid on dead `out` region),
//   folded by k_reduce. (Baseline's 4.2M lane-atomics showed as ~140MB of extra
//   WRITE_SIZE = memory-side RMW; suspected throughput limiter.)
// LDS 48KB -> 3 blocks/CU; waves_per_eu(3,3) pins VGPR budget to 168.
__global__ __attribute__((amdgpu_flat_work_group_size(256, 256), amdgpu_waves_per_eu(3, 3)))
void k_slice2(const short* __restrict__ kv, const short* __restrict__ wtq_bf,
              const float* __restrict__ alpha, float* __restrict__ sw_out,
              short* __restrict__ swT, float* __restrict__ pnum, float* __restrict__ pws) {
    __shared__ __attribute__((aligned(16))) short wT_s[M_ * 256];    // 16 KB [m][n^swz(m)]
    __shared__ __attribute__((aligned(16))) short xvT_s[D_ * 256];   // 32 KB [d][n^swz(d)]
    const int t = threadIdx.x;
    const int bx = blockIdx.x;
    const int chunk = bx & 63;
    const int h = (bx >> 6) & 7;
    const int b = bx >> 9;
    const int w = t >> 6;
    const int L = t & 63;
    const int lm = L & 15;
    const int g = L >> 4;
    const int n0 = chunk * 256;
    const size_t rowb = (size_t)(b * N_ + n0);
    const float al = alpha[h];

    // xv row for token n0+t -> regs (in flight across phase 1)
    short8 xv8[8];
    const short8* xvp = (const short8*)(kv + (rowb + t) * 1024 + HID_ + h * 64);
#pragma unroll
    for (int i = 0; i < 8; ++i) xv8[i] = xvp[i];

    // B fragments (wtq_bf[h][m][d]): frag[mt][ks], lane: col m=mt*16+lm, k=ks*32+g*8
    short8 bq[2][2];
    const short* wq = wtq_bf + h * (M_ * D_);
#pragma unroll
    for (int mt = 0; mt < 2; ++mt)
#pragma unroll
        for (int ks = 0; ks < 2; ++ks)
            bq[mt][ks] = *(const short8*)(wq + (mt * 16 + lm) * 64 + ks * 32 + g * 8);

    // ---- phase 1: scores. Wave w owns tokens [w*64, w*64+64)
    f32x4 s[4][2];
#pragma unroll
    for (int nt = 0; nt < 4; ++nt)
#pragma unroll
        for (int mt = 0; mt < 2; ++mt) s[nt][mt] = (f32x4){0.f, 0.f, 0.f, 0.f};
#pragma unroll
    for (int ks = 0; ks < 2; ++ks) {
        short8 aq[4];  // A-frag: lane row = lm (token nt*16+lm), k = ks*32+g*8
#pragma unroll
        for (int nt = 0; nt < 4; ++nt)
            aq[nt] = *(const short8*)(kv + (rowb + w * 64 + nt * 16 + lm) * 1024 +
                                      h * 64 + ks * 32 + g * 8);
#pragma unroll
        for (int nt = 0; nt < 4; ++nt)
#pragma unroll
            for (int mt = 0; mt < 2; ++mt)
                s[nt][mt] = __builtin_amdgcn_mfma_f32_16x16x32_bf16(aq[nt], bq[mt][ks], s[nt][mt], 0, 0, 0);
    }

    // ---- softmax over m. Lane holds token (w*64+nt*16+g*4+r), m = mt*16+lm.
#pragma unroll
    for (int nt = 0; nt < 4; ++nt)
#pragma unroll
        for (int r = 0; r < 4; ++r) {
            float v0 = s[nt][0][r] * al, v1 = s[nt][1][r] * al;
            float mx = fmaxf(v0, v1);
#pragma unroll
            for (int d2 = 1; d2 < 16; d2 <<= 1) mx = fmaxf(mx, __shfl_xor(mx, d2));
            float e0 = __expf(v0 - mx), e1 = __expf(v1 - mx);
            float sm = e0 + e1;
#pragma unroll
            for (int d2 = 1; d2 < 16; d2 <<= 1) sm += __shfl_xor(sm, d2);
            float inv = 1.f / sm;
            s[nt][0][r] = e0 * inv;
            s[nt][1][r] = e1 * inv;
        }

    // ---- sw_out stores (full-line f32x4), wT LDS writes (bf16 swizzled), wsum partials
    float ws0 = 0.f, ws1 = 0.f;
#pragma unroll
    for (int nt = 0; nt < 4; ++nt) {
        const int nn = w * 64 + nt * 16 + g * 4;  // +r vector
#pragma unroll
        for (int mt = 0; mt < 2; ++mt) {
            const int m = mt * 16 + lm;
            *(f32x4*)(sw_out + ((size_t)((b * 8 + h) * 32 + m)) * N_ + n0 + nn) = s[nt][mt];
            float w4 = s[nt][mt][0] + s[nt][mt][1] + s[nt][mt][2] + s[nt][mt][3];
            if (mt == 0) ws0 += w4; else ws1 += w4;
            unsigned lo = pack2(s[nt][mt][0], s[nt][mt][1]);
            unsigned hi = pack2(s[nt][mt][2], s[nt][mt][3]);
            *(uint2*)(wT_s + m * 256 + (nn ^ ((m & 7) << 3))) = make_uint2(lo, hi);
        }
    }

    // ---- xvT transpose write: thread t = token, d = i*8+j, swz granule 8 shorts
#pragma unroll
    for (int i = 0; i < 8; ++i)
#pragma unroll
        for (int j = 0; j < 8; ++j)
            xvT_s[(i * 8 + j) * 256 + (t ^ (j << 3))] = xv8[i][j];

    __syncthreads();

    // ---- phase 2: wave w owns d-cols [w*16, w*16+16), K = 256 tokens
    const int dcol = w * 16 + lm;
    f32x4 acc2[2];
    acc2[0] = (f32x4){0.f, 0.f, 0.f, 0.f};
    acc2[1] = (f32x4){0.f, 0.f, 0.f, 0.f};
#pragma unroll
    for (int ks = 0; ks < 8; ++ks) {
        const int kb = ks * 32 + g * 8;
        short8 bv = *(const short8*)(xvT_s + dcol * 256 + (kb ^ ((lm & 7) << 3)));
#pragma unroll
        for (int mt = 0; mt < 2; ++mt) {
            const int m = mt * 16 + lm;
            short8 av = *(const short8*)(wT_s + m * 256 + (kb ^ ((lm & 7) << 3)));
            acc2[mt] = __builtin_amdgcn_mfma_f32_16x16x32_bf16(av, bv, acc2[mt], 0, 0, 0);
        }
    }

    // ---- swT: token-major copy of wT (thread t = token)
    {
        unsigned pk[16];
#pragma unroll
        for (int mp = 0; mp < 16; ++mp) {
            unsigned a0 = (unsigned short)wT_s[(2 * mp) * 256 + (t ^ (((2 * mp) & 7) << 3))];
            unsigned a1 = (unsigned short)wT_s[(2 * mp + 1) * 256 + (t ^ (((2 * mp + 1) & 7) << 3))];
            pk[mp] = a0 | (a1 << 16);
        }
        short8* swtp = (short8*)(swT + (rowb + t) * 256 + h * 32);
#pragma unroll
        for (int q = 0; q < 4; ++q) {
            short8 v;
            v[0] = (short)(pk[4 * q] & 0xffff);     v[1] = (short)(pk[4 * q] >> 16);
            v[2] = (short)(pk[4 * q + 1] & 0xffff); v[3] = (short)(pk[4 * q + 1] >> 16);
            v[4] = (short)(pk[4 * q + 2] & 0xffff); v[5] = (short)(pk[4 * q + 2] >> 16);
            v[6] = (short)(pk[4 * q + 3] & 0xffff); v[7] = (short)(pk[4 * q + 3] >> 16);
            swtp[q] = v;
        }
    }

    // ---- per-block partials (non-atomic). num D-layout: row m = mt*16+g*4+r, col dcol.
    float* pn = pnum + ((size_t)((b * 8 + h) * 64 + chunk)) * 2048;
#pragma unroll
    for (int mt = 0; mt < 2; ++mt)
#pragma unroll
        for (int r = 0; r < 4; ++r)
            pn[(mt * 16 + g * 4 + r) * 64 + dcol] = acc2[mt][r];

    ws0 += __shfl_xor(ws0, 16); ws0 += __shfl_xor(ws0, 32);
    ws1 += __shfl_xor(ws1, 16); ws1 += __shfl_xor(ws1, 32);
    if (L < 16) {
        float* pw = pws + (((size_t)((b * 8 + h) * 64 + chunk)) * 4 + w) * 32;
        pw[lm] = ws0;
        pw[16 + lm] = ws1;
    }
}

// ------------------- fold 64 chunk-partials: num (blocks 0-255), wsum (blocks 256-259)
__global__ __launch_bounds__(256)
void k_reduce(const float* __restrict__ pnum, const float* __restrict__ pws,
              float* __restrict__ num, float* __restrict__ wsum) {
    const int bid = blockIdx.x, t = threadIdx.x;
    if (bid < 256) {
        int e = bid * 256 + t;              // (bh, m*64+d)
        int bh = e >> 11, md = e & 2047;
        const float* p = pnum + (size_t)bh * 64 * 2048 + md;
        float s = 0.f;
#pragma unroll 4
        for (int c = 0; c < 64; ++c) s += p[c * 2048];
        num[e] = s;
    } else {
        int e = (bid - 256) * 256 + t;      // (bh, m), 1024 total
        int bh = e >> 5, m = e & 31;
        const float* p = pws + (size_t)bh * 64 * 4 * 32 + m;
        float s = 0.f;
#pragma unroll 4
        for (int cw = 0; cw < 256; ++cw) s += p[cw * 32];
        wsum[e] = s;
    }
}

// ---------------------------------------------------------------- qkv GEMM (tiny)
__global__ __launch_bounds__(256, 2)
void k_qkv(const float* __restrict__ num, const float* __restrict__ wsum,
           const float* __restrict__ qkv_w, float* __restrict__ qkv) {
    __shared__ float st_s[512 * 32];  // [k][m], 64 KB
    const int t = threadIdx.x;
    const int b = blockIdx.y;
    for (int p = 0; p < 64; ++p) {
        int idx = p * 256 + t;
        int m = idx & 31, k = idx >> 5;
        int h = k >> 6, d = k & 63;
        float wsv = wsum[(b * H_ + h) * M_ + m];
        st_s[k * 32 + m] = num[((size_t)(b * H_ + h) * M_ + m) * 64 + d] / (wsv + 1e-5f);
    }
    __syncthreads();
    const int m = t >> 3;
    const int c0 = blockIdx.x * 64 + (t & 7) * 8;
    float acc[8] = {};
    for (int k = 0; k < 512; ++k) {
        float sv = st_s[k * 32 + m];
        const f32x4* wp = (const f32x4*)(qkv_w + (size_t)k * 1536 + c0);
        f32x4 w0 = wp[0], w1 = wp[1];
        acc[0] += sv * w0[0]; acc[1] += sv * w0[1]; acc[2] += sv * w0[2]; acc[3] += sv * w0[3];
        acc[4] += sv * w1[0]; acc[5] += sv * w1[1]; acc[6] += sv * w1[2]; acc[7] += sv * w1[3];
    }
    float* dst = qkv + (size_t)(b * M_ + m) * 1536 + c0;
#pragma unroll
    for (int i = 0; i < 8; ++i) dst[i] = acc[i];
}

// ---------------------------------------------------------------- MHA (tiny, M=32)
__global__ __launch_bounds__(256)
void k_mha(const float* __restrict__ qkv, float* __restrict__ attn_out,
           float* __restrict__ ot) {
    __shared__ float q_s[32 * 65], k_s[32 * 65], v_s[32 * 65];
    __shared__ float s_s[32 * 33], p_s[32 * 33];
    const int bx = blockIdx.x;
    const int b = bx >> 3, h = bx & 7;
    const int t = threadIdx.x;
    for (int p = 0; p < 8; ++p) {
        int idx = p * 256 + t;
        int m = idx >> 6, d = idx & 63;
        size_t base = (size_t)(b * M_ + m) * 1536 + h * 64 + d;
        q_s[m * 65 + d] = qkv[base];
        k_s[m * 65 + d] = qkv[base + 512];
        v_s[m * 65 + d] = qkv[base + 1024];
    }
    __syncthreads();
    for (int p = 0; p < 4; ++p) {
        int c = p * 256 + t;
        int m = c >> 5, mm = c & 31;
        float a = 0.f;
#pragma unroll
        for (int d = 0; d < 64; ++d) a += q_s[m * 65 + d] * k_s[mm * 65 + d];
        s_s[m * 33 + mm] = a * 0.125f;
    }
    __syncthreads();
    if (t < 32) {
        float mx = -1e30f;
        for (int mm = 0; mm < 32; ++mm) mx = fmaxf(mx, s_s[t * 33 + mm]);
        float sum = 0.f;
        for (int mm = 0; mm < 32; ++mm) {
            float e = __expf(s_s[t * 33 + mm] - mx);
            p_s[t * 33 + mm] = e;
            sum += e;
        }
        float inv = 1.f / sum;
        for (int mm = 0; mm < 32; ++mm) {
            float av = p_s[t * 33 + mm] * inv;
            p_s[t * 33 + mm] = av;
            attn_out[((size_t)(b * H_ + h) * M_ + t) * M_ + mm] = av;
        }
    }
    __syncthreads();
    const int m = t >> 3, d0 = (t & 7) * 8;
    float acc[8] = {};
    for (int mm = 0; mm < 32; ++mm) {
        float av = p_s[m * 33 + mm];
#pragma unroll
        for (int j = 0; j < 8; ++j) acc[j] += av * v_s[mm * 65 + d0 + j];
    }
    float* dst = ot + ((size_t)(b * H_ + h) * M_ + m) * 64 + d0;
#pragma unroll
    for (int j = 0; j < 8; ++j) dst[j] = acc[j];
}

// ------------------------------------- P^T: Pt[b][j][h*32+m]
__global__ __launch_bounds__(256)
void k_p(const float* __restrict__ ot, const float* __restrict__ out_w,
         short* __restrict__ Pt) {
    __shared__ float ot_s[32 * 65];
    const int bh = blockIdx.y;
    const int b = bh >> 3, h = bh & 7;
    const int t = threadIdx.x;
    for (int p = 0; p < 8; ++p) {
        int idx = p * 256 + t;
        int m = idx >> 6, d = idx & 63;
        ot_s[m * 65 + d] = ot[(size_t)bh * (M_ * 64) + idx];
    }
    __syncthreads();
    const int j = blockIdx.x * 128 + (t & 127);
    const int mh = (t >> 7) * 16;
    float acc[16] = {};
    for (int d = 0; d < 64; ++d) {
        float ow = out_w[(size_t)(h * 64 + d) * HID_ + j];
#pragma unroll
        for (int i = 0; i < 16; ++i) acc[i] += ot_s[(mh + i) * 65 + d] * ow;
    }
    short* dst = Pt + ((size_t)b * HID_ + j) * (H_ * M_) + h * M_ + mh;
#pragma unroll
    for (int i = 0; i < 16; i += 2) *(unsigned*)(dst + i) = pack2(acc[i], acc[i + 1]);
}

// ---------------------------------------------------------------- launcher
extern "C" void kernel_launch(void* const* d_in, const int* in_sizes, int n_in,
                              void* d_out, int out_size, void* d_ws, size_t ws_size,
                              hipStream_t stream) {
    const float* x     = (const float*)d_in[0];
    const float* wkv_w = (const float*)d_in[1];
    const float* wkv_b = (const float*)d_in[2];
    const float* wtq   = (const float*)d_in[3];
    const float* alpha = (const float*)d_in[4];
    const float* qkv_w = (const float*)d_in[5];
    const float* out_w = (const float*)d_in[6];
    const float* out_b = (const float*)d_in[7];

    float* out       = (float*)d_out;
    float* sw_out    = out + (size_t)B_ * N_ * HID_;                // 33,554,432
    float* alpha_out = sw_out + (size_t)B_ * H_ * M_ * N_;          // 50,331,648
    float* zeros_out = alpha_out + H_;                              // 50,331,656
    float* attn_out  = zeros_out + H_ * M_;                         // 50,331,912

    // x_bf overlays the sw_out output region (dead until k_slice2 writes it later).
    short* x_bf = (short*)sw_out;                                   // 67,108,864 B
    // partials overlay the `out` region (dead until final GEMM writes it last):
    float* pnum = out;                                              // 16 MB (32*64*2048 f32)
    float* pws  = out + 4194304;                                    //  1 MB (32*64*4*32 f32)

    char* ws = (char*)d_ws;
    short* kv   = (short*)(ws);                // 134,217,728 B  (B,N,2*HID) bf16
    short* swT  = (short*)(ws + 134217728);    //  33,554,432 B  (B,N,H*M)   bf16
    short* wkvT = (short*)(ws + 167772160);    //   1,048,576 B  (1024,512)  bf16
    short* Pt   = (short*)(ws + 168820736);    //   1,048,576 B  (B,512,256) bf16
    float* num  = (float*)(ws + 169869312);    //     262,144 B  (B,H,M,64)  f32
    float* wsum = (float*)(ws + 170131456);    //       4,096 B  (B,H,M)     f32
    float* qkvb = (float*)(ws + 170135552);    //     786,432 B  (B,M,1536)  f32
    float* ot   = (float*)(ws + 170921984);    //     262,144 B  (B,H,M,64)  f32
    // wtq_bf overlays ot (dead until k_mha; k_slice2 reads it before that).
    short* wtq_bf = (short*)(ws + 170921984);  //      32,768 B  (H,M,D)     bf16

    k_misc<<<64, 256, 0, stream>>>(alpha, alpha_out, zeros_out, wtq, wtq_bf);
    k_cvt<<<16384, 256, 0, stream>>>(x, x_bf);
    k_wt<<<2048, 256, 0, stream>>>(wkv_w, wkvT);
    // kv = x @ wkv_w + wkv_b   (bf16 out)
    mfma_gemm<true><<<dim3(8, 512), 256, 0, stream>>>(
        x_bf, wkvT, wkv_b, (void*)kv, 512, 1024, 0, 1 << 30);
    k_slice2<<<2048, 256, 0, stream>>>(kv, wtq_bf, alpha, sw_out, swT, pnum, pws);
    k_reduce<<<260, 256, 0, stream>>>(pnum, pws, num, wsum);
    k_qkv<<<dim3(24, 4), 256, 0, stream>>>(num, wsum, qkv_w, qkvb);
    k_mha<<<32, 256, 0, stream>>>(qkvb, attn_out, ot);
    k_p<<<dim3(4, 32), 256, 0, stream>>>(ot, out_w, Pt);
    // out = swT @ Pt^T + out_b   (f32 out)
    mfma_gemm<false><<<dim3(4, 512), 256, 0, stream>>>(
        swT, Pt, out_b, (void*)out, 256, 512, 131072, 16384);
}

// Round 2
// 571.481 us; speedup vs baseline: 1.2606x; 1.0448x over previous
//
#include <hip/hip_runtime.h>

#define B_ 4
#define N_ 16384
#define HID_ 512
#define H_ 8
#define M_ 32
#define D_ 64

typedef __attribute__((ext_vector_type(8))) short short8;
typedef __attribute__((ext_vector_type(4))) float f32x4;

__device__ __forceinline__ short f2bf(float f) {
    unsigned u = __float_as_uint(f);
    u += 0x7fffu + ((u >> 16) & 1u);
    return (short)(u >> 16);
}
__device__ __forceinline__ float bf2f(short s) {
    return __uint_as_float(((unsigned)(unsigned short)s) << 16);
}
__device__ __forceinline__ unsigned pack2(float a, float b) {
    return (unsigned)(unsigned short)f2bf(a) | ((unsigned)(unsigned short)f2bf(b) << 16);
}
__device__ __forceinline__ void gl_lds16(const short* g, short* l) {
    __builtin_amdgcn_global_load_lds((const __attribute__((address_space(1))) unsigned*)g,
                                     (__attribute__((address_space(3))) unsigned*)l, 16, 0, 0);
}

// ------------------------- misc outputs + wtq f32->bf16 (16384 elems, grid 64)
__global__ void k_misc(const float* __restrict__ alpha, float* __restrict__ a_out,
                       float* __restrict__ z_out, const float* __restrict__ wtq,
                       short* __restrict__ wtq_bf) {
    int i = blockIdx.x * 256 + threadIdx.x;
    wtq_bf[i] = f2bf(wtq[i]);
    if (blockIdx.x == 0) {
        int t = threadIdx.x;
        if (t < H_) a_out[t] = alpha[t];
        z_out[t] = 0.f;  // 256 = H_*M_
    }
}

// --------------------------------------------- x (f32) -> bf16, streaming convert
__global__ void k_cvt(const float* __restrict__ src, short* __restrict__ dst) {
    int i = blockIdx.x * 256 + threadIdx.x;   // 8 elements per thread
    const f32x4* s = (const f32x4*)(src) + (size_t)i * 2;
    f32x4 a = s[0], b = s[1];
    short8 o;
    o[0] = f2bf(a[0]); o[1] = f2bf(a[1]); o[2] = f2bf(a[2]); o[3] = f2bf(a[3]);
    o[4] = f2bf(b[0]); o[5] = f2bf(b[1]); o[6] = f2bf(b[2]); o[7] = f2bf(b[3]);
    ((short8*)dst)[i] = o;
}

// ---------------- wkv_w (512x1024 f32) -> (1024x512 bf16), LDS-tiled transpose.
// Old version gathered at 4KB/lane stride (1 line per lane, ~33MB fetched for 2MB).
// 64x64 tiles: both global sides coalesced; LDS padded [64][65] (bank-conflict-free).
__global__ __launch_bounds__(256)
void k_wt(const float* __restrict__ w, short* __restrict__ wt) {
    __shared__ float ls[64][65];
    const int t = threadIdx.x;
    const int n0 = blockIdx.x * 64, k0 = blockIdx.y * 64;
#pragma unroll
    for (int p = 0; p < 16; ++p) {
        int idx = p * 256 + t;
        int kk = idx >> 6, nn = idx & 63;
        ls[kk][nn] = w[(size_t)(k0 + kk) * 1024 + n0 + nn];
    }
    __syncthreads();
#pragma unroll
    for (int p = 0; p < 16; ++p) {
        int idx = p * 256 + t;
        int nn = idx >> 6, kk = idx & 63;
        wt[(size_t)(n0 + nn) * 512 + k0 + kk] = f2bf(ls[kk][nn]);
    }
}

// ---------------------------------------------------------------- MFMA GEMM (m97 structure)
// + T1 XCD swizzle: HW dispatches flat ids round-robin over 8 XCDs; remap so the
// blocks resident on one XCD process CONTIGUOUS tiles (A-panel reuse in its L2).
// Requires nwg % 8 == 0 (kv: 4096, out: 2048 - both ok). lgx = log2(gridDim.x).
template <bool OUT_BF16>
__global__ __launch_bounds__(256, 2)
void mfma_gemm(const short* __restrict__ A, const short* __restrict__ Bt,
               const float* __restrict__ bias, void* __restrict__ Cv,
               int K, int Ncols, int b_stride, int rows_per_b, int lgx) {
    __shared__ short As[128 * 32];
    __shared__ short Bs[128 * 32];
    const int t = threadIdx.x;
    const int nwg = gridDim.x * gridDim.y;
    int id = blockIdx.y * gridDim.x + blockIdx.x;
    id = (id & 7) * (nwg >> 3) + (id >> 3);
    const int col0 = (id & ((1 << lgx) - 1)) * 128;
    const int row0 = (id >> lgx) * 128;
    const short* Bblk = Bt;
    if (b_stride) Bblk += (size_t)(row0 / rows_per_b) * (size_t)b_stride;

    const int r_a = t >> 2;
    const int c_a = (t & 3) << 3;
    const short* Ap = A + (size_t)(row0 + r_a) * K + c_a;
    const short* Bp = Bblk + (size_t)(col0 + r_a) * K + c_a;
    short* As0 = &As[t << 3];
    short* Bs0 = &Bs[t << 3];
    const size_t rowskip = (size_t)64 * K;

    const int w = t >> 6;
    const int L = t & 63;
    const int wm = (w >> 1) << 6;
    const int wn = (w & 1) << 6;
    const int lm = L & 15;
    const int lq = L >> 4;

    f32x4 acc[4][4];
#pragma unroll
    for (int i = 0; i < 4; ++i)
#pragma unroll
        for (int j = 0; j < 4; ++j) acc[i][j] = (f32x4){0.f, 0.f, 0.f, 0.f};

    for (int k0 = 0; k0 < K; k0 += 32) {
        gl_lds16(Ap + k0, As0);
        gl_lds16(Ap + k0 + rowskip, As0 + 2048);
        gl_lds16(Bp + k0, Bs0);
        gl_lds16(Bp + k0 + rowskip, Bs0 + 2048);
        __syncthreads();
        short8 af[4], bfr[4];
#pragma unroll
        for (int i = 0; i < 4; ++i)
            af[i] = *(const short8*)&As[((wm + (i << 4) + lm) << 5) + (lq << 3)];
#pragma unroll
        for (int j = 0; j < 4; ++j)
            bfr[j] = *(const short8*)&Bs[((wn + (j << 4) + lm) << 5) + (lq << 3)];
#pragma unroll
        for (int i = 0; i < 4; ++i)
#pragma unroll
            for (int j = 0; j < 4; ++j)
                acc[i][j] = __builtin_amdgcn_mfma_f32_16x16x32_bf16(af[i], bfr[j], acc[i][j], 0, 0, 0);
        __syncthreads();
    }
#pragma unroll
    for (int i = 0; i < 4; ++i) {
#pragma unroll
        for (int j = 0; j < 4; ++j) {
            const int gr = row0 + wm + (i << 4) + (lq << 2);
            const int gc = col0 + wn + (j << 4) + lm;
            const float bv = bias[gc];
#pragma unroll
            for (int r = 0; r < 4; ++r) {
                float v = acc[i][j][r] + bv;
                if constexpr (OUT_BF16)
                    ((short*)Cv)[(size_t)(gr + r) * Ncols + gc] = f2bf(v);
                else
                    ((float*)Cv)[(size_t)(gr + r) * Ncols + gc] = v;
            }
        }
    }
}

// ---------------------------------------------------------------- score kernel
// Split from old k_slice2: phase 1 only - NO LDS, no barrier -> launch_bounds(256,4)
// gives 16 waves/CU (vs 12 with 48KB LDS) and waves retire independently.
// S(256x32) = xk . wtq_h^T via mfma 16x16x32; softmax over m in-register
// (D-layout puts 16 m across 16 lanes -> shfl_xor reduce). sw_out stored from
// regs as full-line f32x4. wsum partials -> pws.
__global__ __launch_bounds__(256, 4)
void k_score(const short* __restrict__ kv, const short* __restrict__ wtq_bf,
             const float* __restrict__ alpha, float* __restrict__ sw_out,
             float* __restrict__ pws) {
    const int t = threadIdx.x;
    const int bx = blockIdx.x;
    const int chunk = bx & 63;
    const int h = (bx >> 6) & 7;
    const int b = bx >> 9;
    const int w = t >> 6;
    const int L = t & 63;
    const int lm = L & 15;
    const int g = L >> 4;
    const int n0 = chunk * 256;
    const size_t rowb = (size_t)(b * N_ + n0);
    const float al = alpha[h];

    // B fragments (wtq_bf[h][m][d]): lane: col m=mt*16+lm, k=ks*32+g*8
    short8 bq[2][2];
    const short* wq = wtq_bf + h * (M_ * D_);
#pragma unroll
    for (int mt = 0; mt < 2; ++mt)
#pragma unroll
        for (int ks = 0; ks < 2; ++ks)
            bq[mt][ks] = *(const short8*)(wq + (mt * 16 + lm) * 64 + ks * 32 + g * 8);

    // scores: wave w owns tokens [w*64, w*64+64)
    f32x4 s[4][2];
#pragma unroll
    for (int nt = 0; nt < 4; ++nt)
#pragma unroll
        for (int mt = 0; mt < 2; ++mt) s[nt][mt] = (f32x4){0.f, 0.f, 0.f, 0.f};
#pragma unroll
    for (int ks = 0; ks < 2; ++ks) {
        short8 aq[4];  // lane row = token nt*16+lm, k = ks*32+g*8
#pragma unroll
        for (int nt = 0; nt < 4; ++nt)
            aq[nt] = *(const short8*)(kv + (rowb + w * 64 + nt * 16 + lm) * 1024 +
                                      h * 64 + ks * 32 + g * 8);
#pragma unroll
        for (int nt = 0; nt < 4; ++nt)
#pragma unroll
            for (int mt = 0; mt < 2; ++mt)
                s[nt][mt] = __builtin_amdgcn_mfma_f32_16x16x32_bf16(aq[nt], bq[mt][ks], s[nt][mt], 0, 0, 0);
    }

    // softmax over m. Lane holds token (w*64+nt*16+g*4+r), m = mt*16+lm.
#pragma unroll
    for (int nt = 0; nt < 4; ++nt)
#pragma unroll
        for (int r = 0; r < 4; ++r) {
            float v0 = s[nt][0][r] * al, v1 = s[nt][1][r] * al;
            float mx = fmaxf(v0, v1);
#pragma unroll
            for (int d2 = 1; d2 < 16; d2 <<= 1) mx = fmaxf(mx, __shfl_xor(mx, d2));
            float e0 = __expf(v0 - mx), e1 = __expf(v1 - mx);
            float sm = e0 + e1;
#pragma unroll
            for (int d2 = 1; d2 < 16; d2 <<= 1) sm += __shfl_xor(sm, d2);
            float inv = 1.f / sm;
            s[nt][0][r] = e0 * inv;
            s[nt][1][r] = e1 * inv;
        }

    // sw_out stores (full 64B lines: 4 consecutive n per lane, 16 n per 4 g-lanes)
    float ws0 = 0.f, ws1 = 0.f;
#pragma unroll
    for (int nt = 0; nt < 4; ++nt) {
        const int nn = w * 64 + nt * 16 + g * 4;
#pragma unroll
        for (int mt = 0; mt < 2; ++mt) {
            const int m = mt * 16 + lm;
            *(f32x4*)(sw_out + ((size_t)((b * 8 + h) * 32 + m)) * N_ + n0 + nn) = s[nt][mt];
            float w4 = s[nt][mt][0] + s[nt][mt][1] + s[nt][mt][2] + s[nt][mt][3];
            if (mt == 0) ws0 += w4; else ws1 += w4;
        }
    }
    ws0 += __shfl_xor(ws0, 16); ws0 += __shfl_xor(ws0, 32);
    ws1 += __shfl_xor(ws1, 16); ws1 += __shfl_xor(ws1, 32);
    if (L < 16) {
        float* pw = pws + (((size_t)((b * 8 + h) * 64 + chunk)) * 4 + w) * 32;
        pw[lm] = ws0;
        pw[16 + lm] = ws1;
    }
}

// ---------------------------------------------------------------- wsum kernel
// Split from old k_slice2: phase 2. Re-reads sw_out COALESCED (f32 rows along n),
// packs bf16 into XOR-swizzled wT_s; stages xvT; num = wT(32x256).xvT^T(256x64)
// via mfma K=256. swT (token-major bf16) emitted from wT_s. Per-block partials
// -> pnum (no atomics). LDS 48KB -> 3 blocks/CU; waves_per_eu(3,3) pins VGPRs.
__global__ __attribute__((amdgpu_flat_work_group_size(256, 256), amdgpu_waves_per_eu(3, 3)))
void k_wsum(const short* __restrict__ kv, const float* __restrict__ sw_out,
            short* __restrict__ swT, float* __restrict__ pnum) {
    __shared__ __attribute__((aligned(16))) short wT_s[M_ * 256];    // 16 KB [m][n^swz(m)]
    __shared__ __attribute__((aligned(16))) short xvT_s[D_ * 256];   // 32 KB [d][n^swz(d)]
    const int t = threadIdx.x;
    const int bx = blockIdx.x;
    const int chunk = bx & 63;
    const int h = (bx >> 6) & 7;
    const int b = bx >> 9;
    const int w = t >> 6;
    const int L = t & 63;
    const int lm = L & 15;
    const int g = L >> 4;
    const int n0 = chunk * 256;
    const size_t rowb = (size_t)(b * N_ + n0);

    // xv row for token n0+t -> regs
    short8 xv8[8];
    const short8* xvp = (const short8*)(kv + (rowb + t) * 1024 + HID_ + h * 64);
#pragma unroll
    for (int i = 0; i < 8; ++i) xv8[i] = xvp[i];

    // stage wT_s from sw_out: thread t handles m = t>>3, n-range (t&7)*32..+31
    {
        const int m = t >> 3, i = t & 7;
        const int xr = (m & 7) << 3;
        const float* rp = sw_out + ((size_t)((b * 8 + h) * 32 + m)) * N_ + n0 + i * 32;
#pragma unroll
        for (int q = 0; q < 4; ++q) {
            f32x4 a = ((const f32x4*)rp)[2 * q];
            f32x4 c = ((const f32x4*)rp)[2 * q + 1];
            int nn = i * 32 + q * 8;
            short8 v;
            v[0] = f2bf(a[0]); v[1] = f2bf(a[1]); v[2] = f2bf(a[2]); v[3] = f2bf(a[3]);
            v[4] = f2bf(c[0]); v[5] = f2bf(c[1]); v[6] = f2bf(c[2]); v[7] = f2bf(c[3]);
            *(short8*)(wT_s + m * 256 + (nn ^ xr)) = v;
        }
    }

    // xvT transpose write: thread t = token, d = i*8+j, swz granule 8 shorts
#pragma unroll
    for (int i = 0; i < 8; ++i)
#pragma unroll
        for (int j = 0; j < 8; ++j)
            xvT_s[(i * 8 + j) * 256 + (t ^ (j << 3))] = xv8[i][j];

    __syncthreads();

    // phase 2: wave w owns d-cols [w*16, w*16+16), K = 256 tokens
    const int dcol = w * 16 + lm;
    f32x4 acc2[2];
    acc2[0] = (f32x4){0.f, 0.f, 0.f, 0.f};
    acc2[1] = (f32x4){0.f, 0.f, 0.f, 0.f};
#pragma unroll
    for (int ks = 0; ks < 8; ++ks) {
        const int kb = ks * 32 + g * 8;
        short8 bv = *(const short8*)(xvT_s + dcol * 256 + (kb ^ ((lm & 7) << 3)));
#pragma unroll
        for (int mt = 0; mt < 2; ++mt) {
            const int m = mt * 16 + lm;
            short8 av = *(const short8*)(wT_s + m * 256 + (kb ^ ((lm & 7) << 3)));
            acc2[mt] = __builtin_amdgcn_mfma_f32_16x16x32_bf16(av, bv, acc2[mt], 0, 0, 0);
        }
    }

    // swT: token-major copy of wT (thread t = token)
    {
        unsigned pk[16];
#pragma unroll
        for (int mp = 0; mp < 16; ++mp) {
            unsigned a0 = (unsigned short)wT_s[(2 * mp) * 256 + (t ^ (((2 * mp) & 7) << 3))];
            unsigned a1 = (unsigned short)wT_s[(2 * mp + 1) * 256 + (t ^ (((2 * mp + 1) & 7) << 3))];
            pk[mp] = a0 | (a1 << 16);
        }
        short8* swtp = (short8*)(swT + (rowb + t) * 256 + h * 32);
#pragma unroll
        for (int q = 0; q < 4; ++q) {
            short8 v;
            v[0] = (short)(pk[4 * q] & 0xffff);     v[1] = (short)(pk[4 * q] >> 16);
            v[2] = (short)(pk[4 * q + 1] & 0xffff); v[3] = (short)(pk[4 * q + 1] >> 16);
            v[4] = (short)(pk[4 * q + 2] & 0xffff); v[5] = (short)(pk[4 * q + 2] >> 16);
            v[6] = (short)(pk[4 * q + 3] & 0xffff); v[7] = (short)(pk[4 * q + 3] >> 16);
            swtp[q] = v;
        }
    }

    // per-block partials (non-atomic). num D-layout: row m = mt*16+g*4+r, col dcol.
    float* pn = pnum + ((size_t)((b * 8 + h) * 64 + chunk)) * 2048;
#pragma unroll
    for (int mt = 0; mt < 2; ++mt)
#pragma unroll
        for (int r = 0; r < 4; ++r)
            pn[(mt * 16 + g * 4 + r) * 64 + dcol] = acc2[mt][r];
}

// ------------------- fold 64 chunk-partials: num (blocks 0-255), wsum (blocks 256-259)
__global__ __launch_bounds__(256)
void k_reduce(const float* __restrict__ pnum, const float* __restrict__ pws,
              float* __restrict__ num, float* __restrict__ wsum) {
    const int bid = blockIdx.x, t = threadIdx.x;
    if (bid < 256) {
        int e = bid * 256 + t;              // (bh, m*64+d)
        int bh = e >> 11, md = e & 2047;
        const float* p = pnum + (size_t)bh * 64 * 2048 + md;
        float s = 0.f;
#pragma unroll 4
        for (int c = 0; c < 64; ++c) s += p[c * 2048];
        num[e] = s;
    } else {
        int e = (bid - 256) * 256 + t;      // (bh, m), 1024 total
        int bh = e >> 5, m = e & 31;
        const float* p = pws + (size_t)bh * 64 * 4 * 32 + m;
        float s = 0.f;
#pragma unroll 4
        for (int cw = 0; cw < 256; ++cw) s += p[cw * 32];
        wsum[e] = s;
    }
}

// ---------------------------------------------------------------- qkv GEMM (tiny)
__global__ __launch_bounds__(256, 2)
void k_qkv(const float* __restrict__ num, const float* __restrict__ wsum,
           const float* __restrict__ qkv_w, float* __restrict__ qkv) {
    __shared__ float st_s[512 * 32];  // [k][m], 64 KB
    const int t = threadIdx.x;
    const int b = blockIdx.y;
    for (int p = 0; p < 64; ++p) {
        int idx = p * 256 + t;
        int m = idx & 31, k = idx >> 5;
        int h = k >> 6, d = k & 63;
        float wsv = wsum[(b * H_ + h) * M_ + m];
        st_s[k * 32 + m] = num[((size_t)(b * H_ + h) * M_ + m) * 64 + d] / (wsv + 1e-5f);
    }
    __syncthreads();
    const int m = t >> 3;
    const int c0 = blockIdx.x * 64 + (t & 7) * 8;
    float acc[8] = {};
    for (int k = 0; k < 512; ++k) {
        float sv = st_s[k * 32 + m];
        const f32x4* wp = (const f32x4*)(qkv_w + (size_t)k * 1536 + c0);
        f32x4 w0 = wp[0], w1 = wp[1];
        acc[0] += sv * w0[0]; acc[1] += sv * w0[1]; acc[2] += sv * w0[2]; acc[3] += sv * w0[3];
        acc[4] += sv * w1[0]; acc[5] += sv * w1[1]; acc[6] += sv * w1[2]; acc[7] += sv * w1[3];
    }
    float* dst = qkv + (size_t)(b * M_ + m) * 1536 + c0;
#pragma unroll
    for (int i = 0; i < 8; ++i) dst[i] = acc[i];
}

// ---------------------------------------------------------------- MHA (tiny, M=32)
__global__ __launch_bounds__(256)
void k_mha(const float* __restrict__ qkv, float* __restrict__ attn_out,
           float* __restrict__ ot) {
    __shared__ float q_s[32 * 65], k_s[32 * 65], v_s[32 * 65];
    __shared__ float s_s[32 * 33], p_s[32 * 33];
    const int bx = blockIdx.x;
    const int b = bx >> 3, h = bx & 7;
    const int t = threadIdx.x;
    for (int p = 0; p < 8; ++p) {
        int idx = p * 256 + t;
        int m = idx >> 6, d = idx & 63;
        size_t base = (size_t)(b * M_ + m) * 1536 + h * 64 + d;
        q_s[m * 65 + d] = qkv[base];
        k_s[m * 65 + d] = qkv[base + 512];
        v_s[m * 65 + d] = qkv[base + 1024];
    }
    __syncthreads();
    for (int p = 0; p < 4; ++p) {
        int c = p * 256 + t;
        int m = c >> 5, mm = c & 31;
        float a = 0.f;
#pragma unroll
        for (int d = 0; d < 64; ++d) a += q_s[m * 65 + d] * k_s[mm * 65 + d];
        s_s[m * 33 + mm] = a * 0.125f;
    }
    __syncthreads();
    if (t < 32) {
        float mx = -1e30f;
        for (int mm = 0; mm < 32; ++mm) mx = fmaxf(mx, s_s[t * 33 + mm]);
        float sum = 0.f;
        for (int mm = 0; mm < 32; ++mm) {
            float e = __expf(s_s[t * 33 + mm] - mx);
            p_s[t * 33 + mm] = e;
            sum += e;
        }
        float inv = 1.f / sum;
        for (int mm = 0; mm < 32; ++mm) {
            float av = p_s[t * 33 + mm] * inv;
            p_s[t * 33 + mm] = av;
            attn_out[((size_t)(b * H_ + h) * M_ + t) * M_ + mm] = av;
        }
    }
    __syncthreads();
    const int m = t >> 3, d0 = (t & 7) * 8;
    float acc[8] = {};
    for (int mm = 0; mm < 32; ++mm) {
        float av = p_s[m * 33 + mm];
#pragma unroll
        for (int j = 0; j < 8; ++j) acc[j] += av * v_s[mm * 65 + d0 + j];
    }
    float* dst = ot + ((size_t)(b * H_ + h) * M_ + m) * 64 + d0;
#pragma unroll
    for (int j = 0; j < 8; ++j) dst[j] = acc[j];
}

// ------------------------------------- P^T: Pt[b][j][h*32+m]
__global__ __launch_bounds__(256)
void k_p(const float* __restrict__ ot, const float* __restrict__ out_w,
         short* __restrict__ Pt) {
    __shared__ float ot_s[32 * 65];
    const int bh = blockIdx.y;
    const int b = bh >> 3, h = bh & 7;
    const int t = threadIdx.x;
    for (int p = 0; p < 8; ++p) {
        int idx = p * 256 + t;
        int m = idx >> 6, d = idx & 63;
        ot_s[m * 65 + d] = ot[(size_t)bh * (M_ * 64) + idx];
    }
    __syncthreads();
    const int j = blockIdx.x * 128 + (t & 127);
    const int mh = (t >> 7) * 16;
    float acc[16] = {};
    for (int d = 0; d < 64; ++d) {
        float ow = out_w[(size_t)(h * 64 + d) * HID_ + j];
#pragma unroll
        for (int i = 0; i < 16; ++i) acc[i] += ot_s[(mh + i) * 65 + d] * ow;
    }
    short* dst = Pt + ((size_t)b * HID_ + j) * (H_ * M_) + h * M_ + mh;
#pragma unroll
    for (int i = 0; i < 16; i += 2) *(unsigned*)(dst + i) = pack2(acc[i], acc[i + 1]);
}

// ---------------------------------------------------------------- launcher
extern "C" void kernel_launch(void* const* d_in, const int* in_sizes, int n_in,
                              void* d_out, int out_size, void* d_ws, size_t ws_size,
                              hipStream_t stream) {
    const float* x     = (const float*)d_in[0];
    const float* wkv_w = (const float*)d_in[1];
    const float* wkv_b = (const float*)d_in[2];
    const float* wtq   = (const float*)d_in[3];
    const float* alpha = (const float*)d_in[4];
    const float* qkv_w = (const float*)d_in[5];
    const float* out_w = (const float*)d_in[6];
    const float* out_b = (const float*)d_in[7];

    float* out       = (float*)d_out;
    float* sw_out    = out + (size_t)B_ * N_ * HID_;                // 33,554,432
    float* alpha_out = sw_out + (size_t)B_ * H_ * M_ * N_;          // 50,331,648
    float* zeros_out = alpha_out + H_;                              // 50,331,656
    float* attn_out  = zeros_out + H_ * M_;                         // 50,331,912

    // x_bf overlays the sw_out output region (dead until k_score writes it later).
    short* x_bf = (short*)sw_out;                                   // 67,108,864 B
    // partials overlay the `out` region (dead until final GEMM writes it last):
    float* pnum = out;                                              // 16 MB (32*64*2048 f32)
    float* pws  = out + 4194304;                                    //  1 MB (32*64*4*32 f32)

    char* ws = (char*)d_ws;
    short* kv   = (short*)(ws);                // 134,217,728 B  (B,N,2*HID) bf16
    short* swT  = (short*)(ws + 134217728);    //  33,554,432 B  (B,N,H*M)   bf16
    short* wkvT = (short*)(ws + 167772160);    //   1,048,576 B  (1024,512)  bf16
    short* Pt   = (short*)(ws + 168820736);    //   1,048,576 B  (B,512,256) bf16
    float* num  = (float*)(ws + 169869312);    //     262,144 B  (B,H,M,64)  f32
    float* wsum = (float*)(ws + 170131456);    //       4,096 B  (B,H,M)     f32
    float* qkvb = (float*)(ws + 170135552);    //     786,432 B  (B,M,1536)  f32
    float* ot   = (float*)(ws + 170921984);    //     262,144 B  (B,H,M,64)  f32
    // wtq_bf overlays ot (dead until k_mha; k_score reads it before that).
    short* wtq_bf = (short*)(ws + 170921984);  //      32,768 B  (H,M,D)     bf16

    k_misc<<<64, 256, 0, stream>>>(alpha, alpha_out, zeros_out, wtq, wtq_bf);
    k_cvt<<<16384, 256, 0, stream>>>(x, x_bf);
    k_wt<<<dim3(16, 8), 256, 0, stream>>>(wkv_w, wkvT);
    // kv = x @ wkv_w + wkv_b   (bf16 out)
    mfma_gemm<true><<<dim3(8, 512), 256, 0, stream>>>(
        x_bf, wkvT, wkv_b, (void*)kv, 512, 1024, 0, 1 << 30, 3);
    k_score<<<2048, 256, 0, stream>>>(kv, wtq_bf, alpha, sw_out, pws);
    k_wsum<<<2048, 256, 0, stream>>>(kv, sw_out, swT, pnum);
    k_reduce<<<260, 256, 0, stream>>>(pnum, pws, num, wsum);
    k_qkv<<<dim3(24, 4), 256, 0, stream>>>(num, wsum, qkv_w, qkvb);
    k_mha<<<32, 256, 0, stream>>>(qkvb, attn_out, ot);
    k_p<<<dim3(4, 32), 256, 0, stream>>>(ot, out_w, Pt);
    // out = swT @ Pt^T + out_b   (f32 out)
    mfma_gemm<false><<<dim3(4, 512), 256, 0, stream>>>(
        swT, Pt, out_b, (void*)out, 256, 512, 131072, 16384, 2);
}